// Round 1
// baseline (1201.983 us; speedup 1.0000x reference)
//
#include <hip/hip_runtime.h>
#include <hip/hip_bf16.h>
#include <math.h>

// Problem constants
#define BATCH 8
#define NSEQ  1024
#define DIMM  768
#define NHEAD 12
#define DHEAD 64
#define SCALE 0.125f           // DHEAD^-0.5
#define ROWS  (BATCH * NSEQ)   // 8192

// ---------------------------------------------------------------- LayerNorm
__global__ __launch_bounds__(256) void ln_kernel(const float* __restrict__ x,
                                                 const float* __restrict__ g,
                                                 const float* __restrict__ bta,
                                                 float* __restrict__ y) {
    __shared__ float ps[4], pq[4];
    __shared__ float mean_s, rstd_s;
    int row = blockIdx.x;
    int tid = threadIdx.x;
    const float* xr = x + (size_t)row * DIMM;
    float v[3];
    float s = 0.f, sq = 0.f;
#pragma unroll
    for (int i = 0; i < 3; ++i) {
        v[i] = xr[tid + 256 * i];
        s += v[i];
        sq += v[i] * v[i];
    }
#pragma unroll
    for (int off = 32; off >= 1; off >>= 1) {
        s  += __shfl_down(s, off);
        sq += __shfl_down(sq, off);
    }
    int wid = tid >> 6, lane = tid & 63;
    if (lane == 0) { ps[wid] = s; pq[wid] = sq; }
    __syncthreads();
    if (tid == 0) {
        float S = ps[0] + ps[1] + ps[2] + ps[3];
        float Q = pq[0] + pq[1] + pq[2] + pq[3];
        float mean = S * (1.0f / DIMM);
        float var  = Q * (1.0f / DIMM) - mean * mean;
        mean_s = mean;
        rstd_s = rsqrtf(fmaxf(var, 0.f) + 1e-5f);
    }
    __syncthreads();
    float mean = mean_s, rstd = rstd_s;
    float* yr = y + (size_t)row * DIMM;
#pragma unroll
    for (int i = 0; i < 3; ++i) {
        int c = tid + 256 * i;
        yr[c] = (v[i] - mean) * rstd * g[c] + bta[c];
    }
}

// ------------------------------------------------------- fp32 tiled GEMM
// C[M,Nn] = A[M,K] @ B[K,Nn] (+ bias). Row-major everywhere.
#define GBM 64
#define GBN 64
#define GBK 16

__global__ __launch_bounds__(256) void gemm_kernel(const float* __restrict__ A,
                                                   const float* __restrict__ Bm,
                                                   const float* __restrict__ bias,
                                                   float* __restrict__ C,
                                                   int M, int Nn, int K) {
    __shared__ float As[GBK][GBM + 4];   // stride 68 floats -> 16B aligned rows
    __shared__ float Bs[GBK][GBN + 4];
    int tid = threadIdx.x;
    int tx = tid & 15, ty = tid >> 4;
    int n0 = blockIdx.x * GBN, m0 = blockIdx.y * GBM;
    float acc[4][4] = {};

    int ar = tid >> 2;          // A tile row 0..63
    int ak = (tid & 3) * 4;     // A tile k-quad
    int bk = tid >> 4;          // B tile k row 0..15
    int bn = (tid & 15) * 4;    // B tile col quad

    for (int k0 = 0; k0 < K; k0 += GBK) {
        float4 av = *(const float4*)&A[(size_t)(m0 + ar) * K + k0 + ak];
        float4 bv = *(const float4*)&Bm[(size_t)(k0 + bk) * Nn + n0 + bn];
        __syncthreads();   // guard previous iteration's LDS reads
        As[ak + 0][ar] = av.x;
        As[ak + 1][ar] = av.y;
        As[ak + 2][ar] = av.z;
        As[ak + 3][ar] = av.w;
        *(float4*)&Bs[bk][bn] = bv;
        __syncthreads();
#pragma unroll
        for (int kk = 0; kk < GBK; ++kk) {
            float4 a4 = *(const float4*)&As[kk][ty * 4];
            float4 b4 = *(const float4*)&Bs[kk][tx * 4];
            float aa[4] = {a4.x, a4.y, a4.z, a4.w};
            float bb[4] = {b4.x, b4.y, b4.z, b4.w};
#pragma unroll
            for (int i = 0; i < 4; ++i)
#pragma unroll
                for (int j = 0; j < 4; ++j)
                    acc[i][j] += aa[i] * bb[j];
        }
    }
    float4 bb4 = make_float4(0.f, 0.f, 0.f, 0.f);
    if (bias) bb4 = *(const float4*)&bias[n0 + tx * 4];
#pragma unroll
    for (int i = 0; i < 4; ++i) {
        float4 o;
        o.x = acc[i][0] + bb4.x;
        o.y = acc[i][1] + bb4.y;
        o.z = acc[i][2] + bb4.z;
        o.w = acc[i][3] + bb4.w;
        *(float4*)&C[(size_t)(m0 + ty * 4 + i) * Nn + n0 + tx * 4] = o;
    }
}

// ------------------------------------------------- fused flash attention
// qkv: [ROWS, 2304] with q|k|v parts at col offsets 0|768|1536, head h at h*64.
// rpb: [NHEAD, NSEQ, NSEQ]. out: [ROWS, DIMM] (b,n,h,d) layout.
#define ABM 32
#define ABN 64

__global__ __launch_bounds__(256) void attn_kernel(const float* __restrict__ qkv,
                                                   const float* __restrict__ rpb,
                                                   float* __restrict__ outb) {
    __shared__ float Qs[ABM][DHEAD + 4];
    __shared__ float Ks[ABN][DHEAD + 4];
    __shared__ float Vs[ABN][DHEAD + 4];
    __shared__ float Ss[ABM][ABN + 4];
    __shared__ float row_m[ABM], row_l[ABM], row_alpha[ABM], row_newm[ABM];

    int tid = threadIdx.x;
    const int nb = NSEQ / ABM;            // 32 query tiles
    int bh = blockIdx.x / nb;
    int mt = blockIdx.x % nb;
    int b  = bh / NHEAD;
    int h  = bh % NHEAD;
    int m0 = mt * ABM;

    int r   = tid >> 3;   // 0..31 query row within tile
    int sub = tid & 7;    // 0..7

    // load Q tile, pre-scaled
    for (int i = tid; i < ABM * 16; i += 256) {
        int row = i >> 4, d4 = (i & 15) * 4;
        float4 v = *(const float4*)&qkv[((size_t)(b * NSEQ + m0 + row)) * 2304 + h * DHEAD + d4];
        v.x *= SCALE; v.y *= SCALE; v.z *= SCALE; v.w *= SCALE;
        *(float4*)&Qs[row][d4] = v;
    }
    if (tid < ABM) { row_m[tid] = -INFINITY; row_l[tid] = 0.f; }
    float Oacc[8] = {};

    for (int t = 0; t < NSEQ / ABN; ++t) {
        int k0 = t * ABN;
        __syncthreads();   // guard LDS reuse (also covers Q load / m,l init at t=0)
        for (int i = tid; i < ABN * 16; i += 256) {
            int row = i >> 4, d4 = (i & 15) * 4;
            size_t base = ((size_t)(b * NSEQ + k0 + row)) * 2304 + h * DHEAD + d4;
            *(float4*)&Ks[row][d4] = *(const float4*)&qkv[base + 768];
            *(float4*)&Vs[row][d4] = *(const float4*)&qkv[base + 1536];
        }
        __syncthreads();

        // S = Q K^T (+rpb); thread computes cols j = sub + 8*jj
        float acc[8] = {};
#pragma unroll
        for (int d4 = 0; d4 < 16; ++d4) {
            float4 q4 = *(const float4*)&Qs[r][d4 * 4];
#pragma unroll
            for (int jj = 0; jj < 8; ++jj) {
                float4 k4 = *(const float4*)&Ks[sub + 8 * jj][d4 * 4];
                acc[jj] += q4.x * k4.x + q4.y * k4.y + q4.z * k4.z + q4.w * k4.w;
            }
        }
        const float* rpb_row = &rpb[((size_t)h * NSEQ + (m0 + r)) * NSEQ + k0];
#pragma unroll
        for (int jj = 0; jj < 8; ++jj)
            Ss[r][sub + 8 * jj] = acc[jj] + rpb_row[sub + 8 * jj];
        __syncthreads();

        if (tid < ABM) {
            float mx = -INFINITY;
            for (int j = 0; j < ABN; ++j) mx = fmaxf(mx, Ss[tid][j]);
            float mo = row_m[tid];
            float nm = fmaxf(mo, mx);
            row_alpha[tid] = __expf(mo - nm);
            row_newm[tid] = nm;
            row_m[tid] = nm;
        }
        __syncthreads();

        {
            float nm = row_newm[r];
#pragma unroll
            for (int jj = 0; jj < 8; ++jj) {
                float p = __expf(Ss[r][sub + 8 * jj] - nm);
                Ss[r][sub + 8 * jj] = p;
            }
        }
        __syncthreads();

        if (tid < ABM) {
            float sum = 0.f;
            for (int j = 0; j < ABN; ++j) sum += Ss[tid][j];
            row_l[tid] = row_l[tid] * row_alpha[tid] + sum;
        }
        // O = O*alpha + P V ; thread owns cols c = sub*8 .. +8 (contiguous)
        float alpha = row_alpha[r];
#pragma unroll
        for (int c = 0; c < 8; ++c) Oacc[c] *= alpha;
        int c0 = sub * 8;
        for (int j = 0; j < ABN; ++j) {
            float p = Ss[r][j];
            float4 v0 = *(const float4*)&Vs[j][c0];
            float4 v1 = *(const float4*)&Vs[j][c0 + 4];
            Oacc[0] += p * v0.x; Oacc[1] += p * v0.y;
            Oacc[2] += p * v0.z; Oacc[3] += p * v0.w;
            Oacc[4] += p * v1.x; Oacc[5] += p * v1.y;
            Oacc[6] += p * v1.z; Oacc[7] += p * v1.w;
        }
    }
    __syncthreads();   // row_l final values
    float inv_l = 1.0f / row_l[r];
    float* dst = &outb[((size_t)(b * NSEQ + m0 + r)) * DIMM + h * DHEAD + sub * 8];
    float4 o0 = make_float4(Oacc[0] * inv_l, Oacc[1] * inv_l, Oacc[2] * inv_l, Oacc[3] * inv_l);
    float4 o1 = make_float4(Oacc[4] * inv_l, Oacc[5] * inv_l, Oacc[6] * inv_l, Oacc[7] * inv_l);
    *(float4*)&dst[0] = o0;
    *(float4*)&dst[4] = o1;
}

// ---------------------------------------------------------------- launch
extern "C" void kernel_launch(void* const* d_in, const int* in_sizes, int n_in,
                              void* d_out, int out_size, void* d_ws, size_t ws_size,
                              hipStream_t stream) {
    const float* x     = (const float*)d_in[0];
    const float* rpb   = (const float*)d_in[1];
    const float* W_qkv = (const float*)d_in[2];
    const float* W_out = (const float*)d_in[3];
    const float* b_out = (const float*)d_in[4];
    const float* ln_g  = (const float*)d_in[5];
    const float* ln_b  = (const float*)d_in[6];
    float* out = (float*)d_out;

    float* qkv = (float*)d_ws;                       // [8192, 2304]
    float* xn  = qkv + (size_t)ROWS * 3 * DIMM;      // [8192, 768]
    float* attn = xn;                                // reuse after QKV GEMM

    ln_kernel<<<ROWS, 256, 0, stream>>>(x, ln_g, ln_b, xn);
    gemm_kernel<<<dim3(3 * DIMM / GBN, ROWS / GBM), 256, 0, stream>>>(
        xn, W_qkv, nullptr, qkv, ROWS, 3 * DIMM, DIMM);
    attn_kernel<<<BATCH * NHEAD * (NSEQ / ABM), 256, 0, stream>>>(qkv, rpb, attn);
    gemm_kernel<<<dim3(DIMM / GBN, ROWS / GBM), 256, 0, stream>>>(
        attn, W_out, b_out, out, ROWS, DIMM, DIMM);
}

// Round 2
// 299.946 us; speedup vs baseline: 4.0073x; 4.0073x over previous
//
#include <hip/hip_runtime.h>
#include <hip/hip_bf16.h>
#include <math.h>

// Problem constants
#define BATCH 8
#define NSEQ  1024
#define DIMM  768
#define NHEAD 12
#define DHEAD 64
#define SCALE 0.125f           // DHEAD^-0.5
#define ROWS  (BATCH * NSEQ)   // 8192

typedef __hip_bfloat16 bf16;
typedef __bf16 bf16x8 __attribute__((ext_vector_type(8)));
typedef float  f32x4  __attribute__((ext_vector_type(4)));

// ---------------------------------------------------------------- LayerNorm (fp32 in, bf16 out)
__global__ __launch_bounds__(256) void ln_kernel(const float* __restrict__ x,
                                                 const float* __restrict__ g,
                                                 const float* __restrict__ bta,
                                                 bf16* __restrict__ y) {
    __shared__ float ps[4], pq[4];
    __shared__ float mean_s, rstd_s;
    int row = blockIdx.x;
    int tid = threadIdx.x;
    const float* xr = x + (size_t)row * DIMM;
    float v[3];
    float s = 0.f, sq = 0.f;
#pragma unroll
    for (int i = 0; i < 3; ++i) {
        v[i] = xr[tid + 256 * i];
        s += v[i];
        sq += v[i] * v[i];
    }
#pragma unroll
    for (int off = 32; off >= 1; off >>= 1) {
        s  += __shfl_down(s, off);
        sq += __shfl_down(sq, off);
    }
    int wid = tid >> 6, lane = tid & 63;
    if (lane == 0) { ps[wid] = s; pq[wid] = sq; }
    __syncthreads();
    if (tid == 0) {
        float S = ps[0] + ps[1] + ps[2] + ps[3];
        float Q = pq[0] + pq[1] + pq[2] + pq[3];
        float mean = S * (1.0f / DIMM);
        float var  = Q * (1.0f / DIMM) - mean * mean;
        mean_s = mean;
        rstd_s = rsqrtf(fmaxf(var, 0.f) + 1e-5f);
    }
    __syncthreads();
    float mean = mean_s, rstd = rstd_s;
    bf16* yr = y + (size_t)row * DIMM;
#pragma unroll
    for (int i = 0; i < 3; ++i) {
        int c = tid + 256 * i;
        yr[c] = __float2bfloat16((v[i] - mean) * rstd * g[c] + bta[c]);
    }
}

// ------------------------------------------- transpose + fp32->bf16: Wt[n][k] = W[k][n]
__global__ __launch_bounds__(256) void transpose_bf16(const float* __restrict__ W,
                                                      bf16* __restrict__ Wt,
                                                      int K, int N) {
    __shared__ float t[32][33];
    int n0 = blockIdx.x * 32, k0 = blockIdx.y * 32;
    int tx = threadIdx.x, ty = threadIdx.y;   // 32, 8
#pragma unroll
    for (int i = 0; i < 32; i += 8)
        t[ty + i][tx] = W[(size_t)(k0 + ty + i) * N + n0 + tx];
    __syncthreads();
#pragma unroll
    for (int i = 0; i < 32; i += 8)
        Wt[(size_t)(n0 + ty + i) * K + k0 + tx] = __float2bfloat16(t[tx][ty + i]);
}

// ------------------------------------------------------- bf16 MFMA GEMM
// C[M,Nn] = A[M,K] @ Bt[Nn,K]^T (+bias). A,Bt bf16 row-major. 128x128 tile, BK=32.
template <bool OUT_BF16>
__global__ __launch_bounds__(256) void gemm_mfma(const bf16* __restrict__ A,
                                                 const bf16* __restrict__ Bt,
                                                 const float* __restrict__ bias,
                                                 void* __restrict__ Cv,
                                                 int M, int Nn, int K) {
    __shared__ bf16 As[128][40];   // +8 pad: frag reads 2-way (free) bank alias
    __shared__ bf16 Bs[128][40];
    int tid = threadIdx.x;
    int wave = tid >> 6, lane = tid & 63, quad = lane >> 4, l16 = lane & 15;
    int wm = (wave >> 1) * 64, wn = (wave & 1) * 64;
    int m0 = blockIdx.y * 128, n0 = blockIdx.x * 128;

    f32x4 acc[4][4] = {};

    int srow = tid >> 1;          // 0..127
    int sk = (tid & 1) * 16;      // 0 or 16 (bf16 elements)
    const bf16* Ap = A  + (size_t)(m0 + srow) * K + sk;
    const bf16* Bp = Bt + (size_t)(n0 + srow) * K + sk;

    for (int k0 = 0; k0 < K; k0 += 32) {
        uint4 a0 = *(const uint4*)(Ap + k0);
        uint4 a1 = *(const uint4*)(Ap + k0 + 8);
        uint4 b0 = *(const uint4*)(Bp + k0);
        uint4 b1 = *(const uint4*)(Bp + k0 + 8);
        __syncthreads();          // guard previous iteration's frag reads
        *(uint4*)&As[srow][sk]     = a0;
        *(uint4*)&As[srow][sk + 8] = a1;
        *(uint4*)&Bs[srow][sk]     = b0;
        *(uint4*)&Bs[srow][sk + 8] = b1;
        __syncthreads();
        bf16x8 af[4], bf_[4];
#pragma unroll
        for (int i = 0; i < 4; ++i) {
            af[i]  = *(const bf16x8*)&As[wm + i * 16 + l16][quad * 8];
            bf_[i] = *(const bf16x8*)&Bs[wn + i * 16 + l16][quad * 8];
        }
#pragma unroll
        for (int mi = 0; mi < 4; ++mi)
#pragma unroll
            for (int ni = 0; ni < 4; ++ni)
                acc[mi][ni] = __builtin_amdgcn_mfma_f32_16x16x32_bf16(
                    af[mi], bf_[ni], acc[mi][ni], 0, 0, 0);
    }

    float bv[4] = {0.f, 0.f, 0.f, 0.f};
    if (!OUT_BF16 && bias) {
#pragma unroll
        for (int ni = 0; ni < 4; ++ni) bv[ni] = bias[n0 + wn + ni * 16 + l16];
    }
#pragma unroll
    for (int mi = 0; mi < 4; ++mi)
#pragma unroll
        for (int reg = 0; reg < 4; ++reg) {
            size_t row = m0 + wm + mi * 16 + quad * 4 + reg;
#pragma unroll
            for (int ni = 0; ni < 4; ++ni) {
                int col = n0 + wn + ni * 16 + l16;
                float val = acc[mi][ni][reg] + bv[ni];
                if (OUT_BF16)
                    ((bf16*)Cv)[row * Nn + col] = __float2bfloat16(val);
                else
                    ((float*)Cv)[row * Nn + col] = val;
            }
        }
}

// ------------------------------------------------- MFMA flash attention
// qkv: [ROWS, 2304] bf16 (q|k|v at 0|768|1536, head h at h*64).
// rpb: [NHEAD, NSEQ, NSEQ] fp32. outb: [ROWS, DIMM] bf16, (b,n,h*64+d).
__global__ __launch_bounds__(256) void attn_mfma(const bf16* __restrict__ qkv,
                                                 const float* __restrict__ rpb,
                                                 bf16* __restrict__ outb) {
    __shared__ bf16 Ks[64][72];     // K rows x DH, +8 pad
    __shared__ bf16 Vt[64][72];     // DH x K rows (transposed), +8 pad
    __shared__ bf16 Ps[4][16][72];  // per-wave P tile (C-layout -> A-layout round trip)

    int tid = threadIdx.x;
    int wave = tid >> 6, lane = tid & 63, quad = lane >> 4, l16 = lane & 15;
    int bid = blockIdx.x;
    int mt = bid & 15;              // 16 Q-tiles of 64 rows
    int bh = bid >> 4;
    int b = bh / NHEAD, h = bh % NHEAD;
    int m0 = mt * 64;

    // Q fragments in registers for the whole kernel (wave owns Q rows wave*16..+16)
    bf16x8 qf0, qf1;
    {
        const bf16* qrow = qkv + (size_t)(b * NSEQ + m0 + wave * 16 + l16) * (3 * DIMM) + h * DHEAD;
        qf0 = *(const bf16x8*)(qrow + quad * 8);
        qf1 = *(const bf16x8*)(qrow + 32 + quad * 8);
    }
    const float* rp = rpb + ((size_t)h * NSEQ + (m0 + wave * 16)) * NSEQ;

    float m_r[4], l_r[4];
    f32x4 acco[4] = {};
#pragma unroll
    for (int r = 0; r < 4; ++r) { m_r[r] = -INFINITY; l_r[r] = 0.f; }

    int srow = tid >> 2;            // 0..63
    int sd = (tid & 3) * 16;        // 0,16,32,48

    for (int kt = 0; kt < 16; ++kt) {
        int k0 = kt * 64;
        const bf16* kbase = qkv + (size_t)(b * NSEQ + k0 + srow) * (3 * DIMM) + DIMM + h * DHEAD + sd;
        uint4 kv0 = *(const uint4*)(kbase);
        uint4 kv1 = *(const uint4*)(kbase + 8);
        uint4 vv0 = *(const uint4*)(kbase + DIMM);
        uint4 vv1 = *(const uint4*)(kbase + DIMM + 8);
        __syncthreads();            // protect previous iteration's Ks/Vt reads
        *(uint4*)&Ks[srow][sd]     = kv0;
        *(uint4*)&Ks[srow][sd + 8] = kv1;
        union { uint4 u[2]; unsigned short us[16]; } vu;
        vu.u[0] = vv0; vu.u[1] = vv1;
#pragma unroll
        for (int j = 0; j < 16; ++j)
            *(unsigned short*)&Vt[sd + j][srow] = vu.us[j];
        __syncthreads();

        // ---- S = Q K^T (C-layout: row=quad*4+reg (Q), col=l16 (K), tile t)
        f32x4 accs[4] = {};
#pragma unroll
        for (int t = 0; t < 4; ++t) {
            bf16x8 kf0 = *(const bf16x8*)&Ks[t * 16 + l16][quad * 8];
            bf16x8 kf1 = *(const bf16x8*)&Ks[t * 16 + l16][32 + quad * 8];
            accs[t] = __builtin_amdgcn_mfma_f32_16x16x32_bf16(qf0, kf0, accs[t], 0, 0, 0);
            accs[t] = __builtin_amdgcn_mfma_f32_16x16x32_bf16(qf1, kf1, accs[t], 0, 0, 0);
        }

        // ---- online softmax on 16 rows per wave, in-register
        float sv[4][4], mx[4];
#pragma unroll
        for (int r = 0; r < 4; ++r) mx[r] = -INFINITY;
#pragma unroll
        for (int t = 0; t < 4; ++t)
#pragma unroll
            for (int r = 0; r < 4; ++r) {
                float s = accs[t][r] * SCALE +
                          rp[(size_t)(quad * 4 + r) * NSEQ + k0 + t * 16 + l16];
                sv[t][r] = s;
                mx[r] = fmaxf(mx[r], s);
            }
#pragma unroll
        for (int off = 1; off < 16; off <<= 1)
#pragma unroll
            for (int r = 0; r < 4; ++r) mx[r] = fmaxf(mx[r], __shfl_xor(mx[r], off));
        float alpha[4], rs[4];
#pragma unroll
        for (int r = 0; r < 4; ++r) {
            float nm = fmaxf(m_r[r], mx[r]);
            alpha[r] = __expf(m_r[r] - nm);
            m_r[r] = nm;
            rs[r] = 0.f;
        }
#pragma unroll
        for (int t = 0; t < 4; ++t)
#pragma unroll
            for (int r = 0; r < 4; ++r) {
                float p = __expf(sv[t][r] - m_r[r]);
                sv[t][r] = p;
                rs[r] += p;
            }
#pragma unroll
        for (int off = 1; off < 16; off <<= 1)
#pragma unroll
            for (int r = 0; r < 4; ++r) rs[r] += __shfl_xor(rs[r], off);
#pragma unroll
        for (int r = 0; r < 4; ++r) l_r[r] = l_r[r] * alpha[r] + rs[r];
#pragma unroll
        for (int dt = 0; dt < 4; ++dt)
#pragma unroll
            for (int r = 0; r < 4; ++r) acco[dt][r] *= alpha[r];

        // ---- P: C-layout -> A-layout via per-wave LDS (bf16)
#pragma unroll
        for (int t = 0; t < 4; ++t)
#pragma unroll
            for (int r = 0; r < 4; ++r)
                Ps[wave][quad * 4 + r][t * 16 + l16] = __float2bfloat16(sv[t][r]);
        __asm__ volatile("s_waitcnt lgkmcnt(0)" ::: "memory");

        // ---- O += P V
#pragma unroll
        for (int s = 0; s < 2; ++s) {
            bf16x8 pf = *(const bf16x8*)&Ps[wave][l16][s * 32 + quad * 8];
#pragma unroll
            for (int dt = 0; dt < 4; ++dt) {
                bf16x8 vf = *(const bf16x8*)&Vt[dt * 16 + l16][s * 32 + quad * 8];
                acco[dt] = __builtin_amdgcn_mfma_f32_16x16x32_bf16(pf, vf, acco[dt], 0, 0, 0);
            }
        }
    }

    // ---- epilogue: O / l, bf16 store
    float invl[4];
#pragma unroll
    for (int r = 0; r < 4; ++r) invl[r] = 1.f / l_r[r];
    bf16* orow = outb + (size_t)(b * NSEQ + m0 + wave * 16) * DIMM + h * DHEAD;
#pragma unroll
    for (int dt = 0; dt < 4; ++dt)
#pragma unroll
        for (int r = 0; r < 4; ++r)
            orow[(size_t)(quad * 4 + r) * DIMM + dt * 16 + l16] =
                __float2bfloat16(acco[dt][r] * invl[r]);
}

// ---------------------------------------------------------------- launch
extern "C" void kernel_launch(void* const* d_in, const int* in_sizes, int n_in,
                              void* d_out, int out_size, void* d_ws, size_t ws_size,
                              hipStream_t stream) {
    const float* x     = (const float*)d_in[0];
    const float* rpb   = (const float*)d_in[1];
    const float* W_qkv = (const float*)d_in[2];
    const float* W_out = (const float*)d_in[3];
    const float* b_out = (const float*)d_in[4];
    const float* ln_g  = (const float*)d_in[5];
    const float* ln_b  = (const float*)d_in[6];
    float* out = (float*)d_out;

    char* p = (char*)d_ws;
    bf16* xn    = (bf16*)p; p += (size_t)ROWS * DIMM * 2;        // 12.6 MB
    bf16* qkv   = (bf16*)p; p += (size_t)ROWS * 3 * DIMM * 2;    // 37.7 MB
    bf16* attn  = (bf16*)p; p += (size_t)ROWS * DIMM * 2;        // 12.6 MB
    bf16* WqkvT = (bf16*)p; p += (size_t)3 * DIMM * DIMM * 2;    // 3.5 MB
    bf16* WoutT = (bf16*)p; p += (size_t)DIMM * DIMM * 2;        // 1.2 MB

    ln_kernel<<<ROWS, 256, 0, stream>>>(x, ln_g, ln_b, xn);
    transpose_bf16<<<dim3(3 * DIMM / 32, DIMM / 32), dim3(32, 8), 0, stream>>>(
        W_qkv, WqkvT, DIMM, 3 * DIMM);
    transpose_bf16<<<dim3(DIMM / 32, DIMM / 32), dim3(32, 8), 0, stream>>>(
        W_out, WoutT, DIMM, DIMM);

    gemm_mfma<true><<<dim3(3 * DIMM / 128, ROWS / 128), 256, 0, stream>>>(
        xn, WqkvT, nullptr, qkv, ROWS, 3 * DIMM, DIMM);

    attn_mfma<<<BATCH * NHEAD * (NSEQ / 64), 256, 0, stream>>>(qkv, rpb, attn);

    gemm_mfma<false><<<dim3(DIMM / 128, ROWS / 128), 256, 0, stream>>>(
        attn, WoutT, b_out, out, ROWS, DIMM, DIMM);
}

// Round 3
// 290.804 us; speedup vs baseline: 4.1333x; 1.0314x over previous
//
#include <hip/hip_runtime.h>
#include <hip/hip_bf16.h>
#include <math.h>

// Problem constants
#define BATCH 8
#define NSEQ  1024
#define DIMM  768
#define NHEAD 12
#define DHEAD 64
#define SCALE 0.125f           // DHEAD^-0.5
#define ROWS  (BATCH * NSEQ)   // 8192

typedef __hip_bfloat16 bf16;
typedef __bf16 bf16x8 __attribute__((ext_vector_type(8)));
typedef float  f32x4  __attribute__((ext_vector_type(4)));

#if __has_builtin(__builtin_amdgcn_global_load_lds)
#define HAVE_GLL 1
typedef __attribute__((address_space(3))) void lds_void_t;
typedef const __attribute__((address_space(1))) void gbl_void_t;
__device__ __forceinline__ void gload16(const void* g, void* l) {
    __builtin_amdgcn_global_load_lds((gbl_void_t*)g, (lds_void_t*)l, 16, 0, 0);
}
#else
#define HAVE_GLL 0
#endif

// ---------------------------------------------------------------- LayerNorm (fp32 in, bf16 out)
__global__ __launch_bounds__(256) void ln_kernel(const float* __restrict__ x,
                                                 const float* __restrict__ g,
                                                 const float* __restrict__ bta,
                                                 bf16* __restrict__ y) {
    __shared__ float ps[4], pq[4];
    __shared__ float mean_s, rstd_s;
    int row = blockIdx.x;
    int tid = threadIdx.x;
    const float* xr = x + (size_t)row * DIMM;
    float v[3];
    float s = 0.f, sq = 0.f;
#pragma unroll
    for (int i = 0; i < 3; ++i) {
        v[i] = xr[tid + 256 * i];
        s += v[i];
        sq += v[i] * v[i];
    }
#pragma unroll
    for (int off = 32; off >= 1; off >>= 1) {
        s  += __shfl_down(s, off);
        sq += __shfl_down(sq, off);
    }
    int wid = tid >> 6, lane = tid & 63;
    if (lane == 0) { ps[wid] = s; pq[wid] = sq; }
    __syncthreads();
    if (tid == 0) {
        float S = ps[0] + ps[1] + ps[2] + ps[3];
        float Q = pq[0] + pq[1] + pq[2] + pq[3];
        float mean = S * (1.0f / DIMM);
        float var  = Q * (1.0f / DIMM) - mean * mean;
        mean_s = mean;
        rstd_s = rsqrtf(fmaxf(var, 0.f) + 1e-5f);
    }
    __syncthreads();
    float mean = mean_s, rstd = rstd_s;
    bf16* yr = y + (size_t)row * DIMM;
#pragma unroll
    for (int i = 0; i < 3; ++i) {
        int c = tid + 256 * i;
        yr[c] = __float2bfloat16((v[i] - mean) * rstd * g[c] + bta[c]);
    }
}

// ------------------------------------------- transpose + fp32->bf16: Wt[n][k] = W[k][n]
__global__ __launch_bounds__(256) void transpose_bf16(const float* __restrict__ W,
                                                      bf16* __restrict__ Wt,
                                                      int K, int N) {
    __shared__ float t[32][33];
    int n0 = blockIdx.x * 32, k0 = blockIdx.y * 32;
    int tx = threadIdx.x, ty = threadIdx.y;   // 32, 8
#pragma unroll
    for (int i = 0; i < 32; i += 8)
        t[ty + i][tx] = W[(size_t)(k0 + ty + i) * N + n0 + tx];
    __syncthreads();
#pragma unroll
    for (int i = 0; i < 32; i += 8)
        Wt[(size_t)(n0 + ty + i) * K + k0 + tx] = __float2bfloat16(t[tx][ty + i]);
}

// ------------------------------------------------------- bf16 MFMA GEMM (m97 structure)
// C[M,Nn] = A[M,K] @ Bt[Nn,K]^T (+bias). 128x128 tile, BK=32, global_load_lds staging.
template <bool OUT_BF16>
__global__ __launch_bounds__(256) void gemm_mfma(const bf16* __restrict__ A,
                                                 const bf16* __restrict__ Bt,
                                                 const float* __restrict__ bias,
                                                 void* __restrict__ Cv,
                                                 int M, int Nn, int K) {
    __shared__ bf16 As[128][32];   // unpadded: lane-linear for global_load_lds
    __shared__ bf16 Bs[128][32];
    int tid = threadIdx.x;
    int wave = tid >> 6, lane = tid & 63, quad = lane >> 4, l16 = lane & 15;
    int wm = (wave >> 1) * 64, wn = (wave & 1) * 64;
    int m0 = blockIdx.y * 128, n0 = blockIdx.x * 128;

    f32x4 acc[4][4] = {};

#if HAVE_GLL
    // lane's 16B chunk: instr i covers rows i*64 + tid/4, col chunk (tid&3)*8
    const char* Ag = (const char*)(A  + (size_t)(m0 + (tid >> 2)) * K + (tid & 3) * 8);
    const char* Bg = (const char*)(Bt + (size_t)(n0 + (tid >> 2)) * K + (tid & 3) * 8);
    char* AsB = (char*)&As[0][0] + tid * 16;
    char* BsB = (char*)&Bs[0][0] + tid * 16;
    const size_t radv = (size_t)64 * K * 2;   // +64 rows

    for (int k0 = 0; k0 < K; k0 += 32) {
        __syncthreads();              // previous tile's frag reads done
        gload16(Ag, AsB);
        gload16(Ag + radv, AsB + 4096);
        gload16(Bg, BsB);
        gload16(Bg + radv, BsB + 4096);
        Ag += 64; Bg += 64;           // 32 bf16
        __syncthreads();              // drains vmcnt -> LDS visible
#else
    int srow = tid >> 1;
    int sk = (tid & 1) * 16;
    const bf16* Ap = A  + (size_t)(m0 + srow) * K + sk;
    const bf16* Bp = Bt + (size_t)(n0 + srow) * K + sk;
    for (int k0 = 0; k0 < K; k0 += 32) {
        uint4 a0 = *(const uint4*)(Ap + k0);
        uint4 a1 = *(const uint4*)(Ap + k0 + 8);
        uint4 b0 = *(const uint4*)(Bp + k0);
        uint4 b1 = *(const uint4*)(Bp + k0 + 8);
        __syncthreads();
        *(uint4*)&As[srow][sk]     = a0;
        *(uint4*)&As[srow][sk + 8] = a1;
        *(uint4*)&Bs[srow][sk]     = b0;
        *(uint4*)&Bs[srow][sk + 8] = b1;
        __syncthreads();
#endif
        bf16x8 af[4], bf_[4];
#pragma unroll
        for (int i = 0; i < 4; ++i) {
            af[i]  = *(const bf16x8*)&As[wm + i * 16 + l16][quad * 8];
            bf_[i] = *(const bf16x8*)&Bs[wn + i * 16 + l16][quad * 8];
        }
#pragma unroll
        for (int mi = 0; mi < 4; ++mi)
#pragma unroll
            for (int ni = 0; ni < 4; ++ni)
                acc[mi][ni] = __builtin_amdgcn_mfma_f32_16x16x32_bf16(
                    af[mi], bf_[ni], acc[mi][ni], 0, 0, 0);
    }

    float bv[4] = {0.f, 0.f, 0.f, 0.f};
    if (!OUT_BF16 && bias) {
#pragma unroll
        for (int ni = 0; ni < 4; ++ni) bv[ni] = bias[n0 + wn + ni * 16 + l16];
    }
#pragma unroll
    for (int mi = 0; mi < 4; ++mi)
#pragma unroll
        for (int reg = 0; reg < 4; ++reg) {
            size_t row = m0 + wm + mi * 16 + quad * 4 + reg;
#pragma unroll
            for (int ni = 0; ni < 4; ++ni) {
                int col = n0 + wn + ni * 16 + l16;
                float val = acc[mi][ni][reg] + bv[ni];
                if (OUT_BF16)
                    ((bf16*)Cv)[row * Nn + col] = __float2bfloat16(val);
                else
                    ((float*)Cv)[row * Nn + col] = val;
            }
        }
}

// ------------------------------------------------- MFMA flash attention
// qkv: [ROWS, 2304] bf16 (q|k|v at 0|768|1536, head h at h*64).
// rpb: [NHEAD, NSEQ, NSEQ] fp32. outb: [ROWS, DIMM] bf16.
__global__ __launch_bounds__(256) void attn_mfma(const bf16* __restrict__ qkv,
                                                 const float* __restrict__ rpb,
                                                 bf16* __restrict__ outb) {
    __shared__ bf16 Ks[64][72];          // K rows x DH, +8 pad
    __shared__ unsigned Vt32[64][36];    // V^T: [d][krow] as dwords (2 krows/dword)
    __shared__ bf16 Ps[4][16][72];       // per-wave P tile (C->A layout round trip)

    int tid = threadIdx.x;
    int wave = tid >> 6, lane = tid & 63, quad = lane >> 4, l16 = lane & 15;
    int bid = blockIdx.x;
    int b  = bid & 7;                    // batch innermost: 8 blocks share rpb stripe
    int r2 = bid >> 3;
    int h  = r2 % NHEAD;
    int mt = r2 / NHEAD;
    int m0 = mt * 64;

    // Q fragments in registers for the whole kernel (wave owns Q rows wave*16..+16)
    bf16x8 qf0, qf1;
    {
        const bf16* qrow = qkv + (size_t)(b * NSEQ + m0 + wave * 16 + l16) * (3 * DIMM) + h * DHEAD;
        qf0 = *(const bf16x8*)(qrow + quad * 8);
        qf1 = *(const bf16x8*)(qrow + 32 + quad * 8);
    }
    const float* rp = rpb + ((size_t)h * NSEQ + (m0 + wave * 16)) * NSEQ;

    // ones B-fragment: column 0 of the virtual ones-matrix -> row-sum via MFMA
    bf16x8 onesf;
#pragma unroll
    for (int e = 0; e < 8; ++e) onesf[e] = (l16 == 0) ? (__bf16)1.0f : (__bf16)0.0f;

    float m_r[4];
    f32x4 accl = {0.f, 0.f, 0.f, 0.f};
    f32x4 acco[4] = {};
#pragma unroll
    for (int r = 0; r < 4; ++r) m_r[r] = -INFINITY;

    int srow = tid >> 2;            // 0..63 (K/V row)
    int sd = (tid & 3) * 16;        // 0,16,32,48
    bool hi = (srow & 1);
    int p2 = srow >> 1;

    const bf16* kbase = qkv + (size_t)(b * NSEQ + srow) * (3 * DIMM) + DIMM + h * DHEAD + sd;
    uint4 kv0 = *(const uint4*)(kbase);
    uint4 kv1 = *(const uint4*)(kbase + 8);
    uint4 vv0 = *(const uint4*)(kbase + DIMM);
    uint4 vv1 = *(const uint4*)(kbase + DIMM + 8);

    for (int kt = 0; kt < 16; ++kt) {
        __syncthreads();            // previous iteration's LDS reads done
        *(uint4*)&Ks[srow][sd]     = kv0;
        *(uint4*)&Ks[srow][sd + 8] = kv1;
        // ---- paired-dword V transpose write (partner = lane^4 holds srow^1)
        {
            union { uint4 u4[2]; unsigned short us[16]; } vu;
            vu.u4[0] = vv0; vu.u4[1] = vv1;
            union { uint4 q; unsigned short h8[8]; } R, Sd;
            Sd.q = hi ? vu.u4[0] : vu.u4[1];   // what partner needs
            R.q.x = __shfl_xor(Sd.q.x, 4);
            R.q.y = __shfl_xor(Sd.q.y, 4);
            R.q.z = __shfl_xor(Sd.q.z, 4);
            R.q.w = __shfl_xor(Sd.q.w, 4);
            if (!hi) {
#pragma unroll
                for (int j = 0; j < 8; ++j)
                    Vt32[sd + j][p2] = (unsigned)vu.us[j] | ((unsigned)R.h8[j] << 16);
            } else {
#pragma unroll
                for (int j = 0; j < 8; ++j)
                    Vt32[sd + 8 + j][p2] = (unsigned)R.h8[j] | ((unsigned)vu.us[8 + j] << 16);
            }
        }
        __syncthreads();

        // ---- prefetch next K/V tile into registers (overlaps compute)
        if (kt + 1 < 16) {
            const bf16* kb2 = kbase + (size_t)(kt + 1) * 64 * (3 * DIMM);
            kv0 = *(const uint4*)(kb2);
            kv1 = *(const uint4*)(kb2 + 8);
            vv0 = *(const uint4*)(kb2 + DIMM);
            vv1 = *(const uint4*)(kb2 + DIMM + 8);
        }
        // ---- rpb loads for this tile
        float rv[4][4];
        const float* rpk = rp + kt * 64;
#pragma unroll
        for (int t = 0; t < 4; ++t)
#pragma unroll
            for (int r = 0; r < 4; ++r)
                rv[t][r] = rpk[(size_t)(quad * 4 + r) * NSEQ + t * 16 + l16];

        // ---- S = Q K^T (C-layout: row=quad*4+reg (Q), col=l16 (K), tile t)
        f32x4 accs[4] = {};
#pragma unroll
        for (int t = 0; t < 4; ++t) {
            bf16x8 kf0 = *(const bf16x8*)&Ks[t * 16 + l16][quad * 8];
            bf16x8 kf1 = *(const bf16x8*)&Ks[t * 16 + l16][32 + quad * 8];
            accs[t] = __builtin_amdgcn_mfma_f32_16x16x32_bf16(qf0, kf0, accs[t], 0, 0, 0);
            accs[t] = __builtin_amdgcn_mfma_f32_16x16x32_bf16(qf1, kf1, accs[t], 0, 0, 0);
        }

        // ---- online softmax (max via shuffles; sum via ones-MFMA below)
        float sv[4][4], mx[4];
#pragma unroll
        for (int r = 0; r < 4; ++r) mx[r] = -INFINITY;
#pragma unroll
        for (int t = 0; t < 4; ++t)
#pragma unroll
            for (int r = 0; r < 4; ++r) {
                float s = accs[t][r] * SCALE + rv[t][r];
                sv[t][r] = s;
                mx[r] = fmaxf(mx[r], s);
            }
#pragma unroll
        for (int off = 1; off < 16; off <<= 1)
#pragma unroll
            for (int r = 0; r < 4; ++r) mx[r] = fmaxf(mx[r], __shfl_xor(mx[r], off));
        float alpha[4];
#pragma unroll
        for (int r = 0; r < 4; ++r) {
            float nm = fmaxf(m_r[r], mx[r]);
            alpha[r] = __expf(m_r[r] - nm);
            m_r[r] = nm;
        }
#pragma unroll
        for (int t = 0; t < 4; ++t)
#pragma unroll
            for (int r = 0; r < 4; ++r)
                sv[t][r] = __expf(sv[t][r] - m_r[r]);
#pragma unroll
        for (int r = 0; r < 4; ++r) accl[r] *= alpha[r];
#pragma unroll
        for (int dt = 0; dt < 4; ++dt)
#pragma unroll
            for (int r = 0; r < 4; ++r) acco[dt][r] *= alpha[r];

        // ---- P: C-layout -> A-layout via per-wave LDS (bf16)
#pragma unroll
        for (int t = 0; t < 4; ++t)
#pragma unroll
            for (int r = 0; r < 4; ++r)
                Ps[wave][quad * 4 + r][t * 16 + l16] = __float2bfloat16(sv[t][r]);
        __asm__ volatile("s_waitcnt lgkmcnt(0)" ::: "memory");

        // ---- O += P V ; l += P @ ones (col 0)
        const bf16* VtB = (const bf16*)&Vt32[0][0];
#pragma unroll
        for (int s = 0; s < 2; ++s) {
            bf16x8 pf = *(const bf16x8*)&Ps[wave][l16][s * 32 + quad * 8];
            accl = __builtin_amdgcn_mfma_f32_16x16x32_bf16(pf, onesf, accl, 0, 0, 0);
#pragma unroll
            for (int dt = 0; dt < 4; ++dt) {
                bf16x8 vf = *(const bf16x8*)(VtB + (size_t)(dt * 16 + l16) * 72 + s * 32 + quad * 8);
                acco[dt] = __builtin_amdgcn_mfma_f32_16x16x32_bf16(pf, vf, acco[dt], 0, 0, 0);
            }
        }
    }

    // ---- epilogue: O / l, bf16 store (l lives at lane quad*16, col 0 of accl)
    float invl[4];
#pragma unroll
    for (int r = 0; r < 4; ++r) {
        float ls = __shfl(accl[r], lane & 48);
        invl[r] = 1.f / ls;
    }
    bf16* orow = outb + (size_t)(b * NSEQ + m0 + wave * 16) * DIMM + h * DHEAD;
#pragma unroll
    for (int dt = 0; dt < 4; ++dt)
#pragma unroll
        for (int r = 0; r < 4; ++r)
            orow[(size_t)(quad * 4 + r) * DIMM + dt * 16 + l16] =
                __float2bfloat16(acco[dt][r] * invl[r]);
}

// ---------------------------------------------------------------- launch
extern "C" void kernel_launch(void* const* d_in, const int* in_sizes, int n_in,
                              void* d_out, int out_size, void* d_ws, size_t ws_size,
                              hipStream_t stream) {
    const float* x     = (const float*)d_in[0];
    const float* rpb   = (const float*)d_in[1];
    const float* W_qkv = (const float*)d_in[2];
    const float* W_out = (const float*)d_in[3];
    const float* b_out = (const float*)d_in[4];
    const float* ln_g  = (const float*)d_in[5];
    const float* ln_b  = (const float*)d_in[6];
    float* out = (float*)d_out;

    char* p = (char*)d_ws;
    bf16* xn    = (bf16*)p; p += (size_t)ROWS * DIMM * 2;
    bf16* qkv   = (bf16*)p; p += (size_t)ROWS * 3 * DIMM * 2;
    bf16* attn  = (bf16*)p; p += (size_t)ROWS * DIMM * 2;
    bf16* WqkvT = (bf16*)p; p += (size_t)3 * DIMM * DIMM * 2;
    bf16* WoutT = (bf16*)p; p += (size_t)DIMM * DIMM * 2;

    ln_kernel<<<ROWS, 256, 0, stream>>>(x, ln_g, ln_b, xn);
    transpose_bf16<<<dim3(3 * DIMM / 32, DIMM / 32), dim3(32, 8), 0, stream>>>(
        W_qkv, WqkvT, DIMM, 3 * DIMM);
    transpose_bf16<<<dim3(DIMM / 32, DIMM / 32), dim3(32, 8), 0, stream>>>(
        W_out, WoutT, DIMM, DIMM);

    gemm_mfma<true><<<dim3(3 * DIMM / 128, ROWS / 128), 256, 0, stream>>>(
        xn, WqkvT, nullptr, qkv, ROWS, 3 * DIMM, DIMM);

    attn_mfma<<<BATCH * NHEAD * (NSEQ / 64), 256, 0, stream>>>(qkv, rpb, attn);

    gemm_mfma<false><<<dim3(DIMM / 128, ROWS / 128), 256, 0, stream>>>(
        attn, WoutT, b_out, out, ROWS, DIMM, DIMM);
}